// Round 10
// baseline (1017.896 us; speedup 1.0000x reference)
//
#include <hip/hip_runtime.h>

#define N_NODES 50000
#define N_EDGES 800000
#define BATCH 8
#define CH 64
#define BC (BATCH * CH)                  // 512 elems per node row (node-major layout)
#define WSZ (CH * CH)
#define NROWS (BATCH * N_NODES)          // 400000 GEMM rows
#define TELEMS ((size_t)NROWS * CH)      // 25.6M elems per t-buffer
#define HIST_BLOCKS ((N_EDGES + 255) / 256)      // 3125
#define CAST_BLOCKS ((int)(TELEMS / 4 / 256))    // 25000
#define PACK_BLOCKS 12
#define NCHUNK ((N_NODES + 63) / 64)             // 782 64-node chunks
#define GG (NCHUNK * 8)                          // out_gemm grid: 6256 blocks

typedef unsigned short u16;
typedef short bf16x8 __attribute__((ext_vector_type(8)));
typedef float f32x4 __attribute__((ext_vector_type(4)));
typedef unsigned short u16x4 __attribute__((ext_vector_type(4)));
typedef unsigned short u16x8 __attribute__((ext_vector_type(8)));

__device__ __forceinline__ u16 f2bf(float f) {          // RNE
    unsigned x = __float_as_uint(f);
    return (u16)((x + 0x7fffu + ((x >> 16) & 1u)) >> 16);
}
__device__ __forceinline__ float b2f(u16 u) {
    return __uint_as_float(((unsigned)u) << 16);
}

// ---------------- CSR build + input prep ----------------

// fused: blocks [0, HIST_BLOCKS) do the dst histogram; the rest transpose-cast
// x fp32 [B,N,C] -> bf16 [N,B,C]. Independent work, overlapped in one launch.
__global__ __launch_bounds__(256) void hist_cast_kernel(
        const int* __restrict__ dst, int* __restrict__ cursor,
        const float* __restrict__ x, u16* __restrict__ xb) {
    int bid = blockIdx.x;
    if (bid < HIST_BLOCKS) {
        int e = bid * 256 + threadIdx.x;
        if (e < N_EDGES) atomicAdd(&cursor[dst[e]], 1);
        return;
    }
    size_t i = (size_t)(bid - HIST_BLOCKS) * 256 + threadIdx.x;   // B*N*16 groups of 4ch
    f32x4 v = __builtin_nontemporal_load((const f32x4*)(x + i * 4));
    int c4 = (int)(i & 15);
    size_t bn = i >> 4;                                  // b*N + n
    int b = (int)(bn / N_NODES);
    int n = (int)(bn - (size_t)b * N_NODES);
    u16x4 o;
    o.x = f2bf(v.x); o.y = f2bf(v.y); o.z = f2bf(v.z); o.w = f2bf(v.w);
    *(u16x4*)(xb + ((size_t)n * BATCH + b) * CH + c4 * 4) = o;   // cached: gather source
}

__global__ void scan_kernel(int* cursor, int* __restrict__ row_ptr, int n) {
    const int T = 1024;
    int tid = threadIdx.x;
    int per = (n + T - 1) / T;
    int s = tid * per;
    int e = s + per; if (e > n) e = n;
    int sum = 0;
    for (int i = s; i < e; ++i) sum += cursor[i];
    __shared__ int lds[1024];
    lds[tid] = sum;
    __syncthreads();
    for (int off = 1; off < 1024; off <<= 1) {
        int t = (tid >= off) ? lds[tid - off] : 0;
        __syncthreads();
        lds[tid] += t;
        __syncthreads();
    }
    int run = lds[tid] - sum;
    for (int i = s; i < e; ++i) {
        int v = cursor[i];
        row_ptr[i] = run;
        cursor[i]  = run;
        run += v;
    }
    if (tid == T - 1) row_ptr[n] = run;
}

// fused: blocks [0, HIST_BLOCKS) scatter edges into CSR slots; the rest pack W
// into the MFMA B-fragment layout (frag id = (k*2+cct)*4+ct; lane holds
// B[k=quad*8+j][col=ct*16+(lane&15)]).
__global__ __launch_bounds__(256) void scatter_pack_kernel(
        const int* __restrict__ dst, const int* __restrict__ src,
        const float* __restrict__ w, int* cursor, int2* __restrict__ edges,
        const float* __restrict__ W, u16* __restrict__ wpack) {
    int bid = blockIdx.x;
    if (bid < HIST_BLOCKS) {
        int e = bid * 256 + threadIdx.x;
        if (e >= N_EDGES) return;
        int d = dst[e];
        int p = atomicAdd(&cursor[d], 1);
        edges[p] = make_int2(src[e], __float_as_int(w[e]));
        return;
    }
    int id = (bid - HIST_BLOCKS) * 256 + threadIdx.x;   // 48 frags * 64 lanes = 3072
    if (id >= 48 * 64) return;
    int lane = id & 63, frag = id >> 6;
    int ct = frag & 3, cct = (frag >> 2) & 1, k = frag >> 3;
    int m = lane & 15, quad = lane >> 4;
    int c = ct * 16 + m;
#pragma unroll
    for (int j = 0; j < 8; ++j) {
        int cc = cct * 32 + quad * 8 + j;
        wpack[(size_t)id * 8 + j] = f2bf(W[k * WSZ + cc * CH + c]);
    }
}

// ---------------- SPMM half-step: wave-per-node, batch-half, node-major ------
// Each SPMM is split into two half-passes over batches [0,4) / [4,8): gather
// working set 25.6 MB. Lane l covers batch half*4 + (l>>4), channels
// (l&15)*4..+4 (8B u16x4 load; wave = 512B contiguous half-row).
template <bool HAS_PREV>
__global__ __launch_bounds__(256) void spmm_kernel(
        const u16* __restrict__ tcur,
        const u16* __restrict__ tprev,
        u16* __restrict__ tnext,
        const int* __restrict__ row_ptr,
        const int2* __restrict__ edges,
        int half) {
    const int node = blockIdx.x * 4 + (threadIdx.x >> 6);
    const int lane = threadIdx.x & 63;
    const size_t lo = (size_t)half * 256 + (size_t)lane * 4;

    float acc[4];
#pragma unroll
    for (int q = 0; q < 4; ++q) acc[q] = 0.f;

    const int beg = row_ptr[node], end = row_ptr[node + 1];
    for (int e0 = beg; e0 < end; e0 += 64) {
        int m = end - e0; if (m > 64) m = 64;
        int2 ev = edges[e0 + (lane < m ? lane : 0)];
        int j = 0;
        for (; j + 4 <= m; j += 4) {                 // no predication, no waste
            int   s0 = __shfl(ev.x, j);
            int   s1 = __shfl(ev.x, j + 1);
            int   s2 = __shfl(ev.x, j + 2);
            int   s3 = __shfl(ev.x, j + 3);
            float w0 = __int_as_float(__shfl(ev.y, j));
            float w1 = __int_as_float(__shfl(ev.y, j + 1));
            float w2 = __int_as_float(__shfl(ev.y, j + 2));
            float w3 = __int_as_float(__shfl(ev.y, j + 3));
            u16x4 v0 = *(const u16x4*)(tcur + (size_t)s0 * BC + lo);
            u16x4 v1 = *(const u16x4*)(tcur + (size_t)s1 * BC + lo);
            u16x4 v2 = *(const u16x4*)(tcur + (size_t)s2 * BC + lo);
            u16x4 v3 = *(const u16x4*)(tcur + (size_t)s3 * BC + lo);
#pragma unroll
            for (int q = 0; q < 4; ++q) acc[q] = fmaf(w0, b2f(v0[q]), acc[q]);
#pragma unroll
            for (int q = 0; q < 4; ++q) acc[q] = fmaf(w1, b2f(v1[q]), acc[q]);
#pragma unroll
            for (int q = 0; q < 4; ++q) acc[q] = fmaf(w2, b2f(v2[q]), acc[q]);
#pragma unroll
            for (int q = 0; q < 4; ++q) acc[q] = fmaf(w3, b2f(v3[q]), acc[q]);
        }
        for (; j < m; ++j) {                         // wave-uniform tail, 0..3 edges
            int   s = __shfl(ev.x, j);
            float w = __int_as_float(__shfl(ev.y, j));
            u16x4 v = *(const u16x4*)(tcur + (size_t)s * BC + lo);
#pragma unroll
            for (int q = 0; q < 4; ++q) acc[q] = fmaf(w, b2f(v[q]), acc[q]);
        }
    }

    const size_t idx = (size_t)node * BC + lo;
    u16x4 o;
    if (HAS_PREV) {
        u16x4 pv = *(const u16x4*)(tprev + idx);
#pragma unroll
        for (int q = 0; q < 4; ++q) o[q] = f2bf(2.f * acc[q] - b2f(pv[q]));
    } else {
#pragma unroll
        for (int q = 0; q < 4; ++q) o[q] = f2bf(acc[q]);
    }
    *(u16x4*)(tnext + idx) = o;   // cached: next half-step's gather source
}

// ---------------- final GEMM: out = bias + sum_k t_k @ W_k (MFMA bf16) ----------------
// Block = (b, 64 consecutive n); wave w owns rows n0+w*16..+16 of batch b.
// A (rows of all NK t-buffers) is async-staged into LDS via global_load_lds
// width-16 (one vmcnt drain per block instead of 12 serialized latencies per
// wave, which is what the compiler produced for the register version — VGPR=52
// proved it sank the loads). LDS dest is linear; bank swizzle (chunk ^= row&7)
// is applied on the per-lane GLOBAL source address and undone on the ds_read.
// C-writes are contiguous per block (b-major tile) — kills the 12.8MB scatter.
// MFMA (k, cct, ct) order and per-lane fragment content unchanged -> per-element
// bit-identical to the previous version. ACCUM: out += ..., else out = bias + ...
template <int NK, bool ACCUM>
__global__ __launch_bounds__(256) void out_gemm(
        const u16* __restrict__ tbase, size_t tstride,
        const u16* __restrict__ wpack,      // already offset by k0*WSZ
        const float* __restrict__ bias,
        float* __restrict__ out) {
    __shared__ u16 smem[NK * 4096];          // NK * 8KB: [NK][64 rows][128B]
    const int tid = threadIdx.x;
    const int wave = tid >> 6, lane = tid & 63;
    const int b  = blockIdx.x & 7;
    const int n0 = (blockIdx.x >> 3) << 6;

    // ---- async stage A: 2*NK rounds x 4KB (256 lanes x 16B, wave = 1KB) ----
#pragma unroll
    for (int rr = 0; rr < 2 * NK; ++rr) {
        int r384 = rr * 32 + (tid >> 3);     // 128B-row index in LDS image
        int k = r384 >> 6;
        int r = r384 & 63;                   // row within the 64-node chunk
        int n = n0 + r; if (n >= N_NODES) n = N_NODES - 1;   // tail clamp (dup read)
        const u16* gsrc = tbase + (size_t)k * tstride
                        + ((size_t)n * 8 + b) * CH
                        + (size_t)(((tid & 7) ^ (r & 7)) * 8);   // inverse swizzle
        u16* ldst = &smem[rr * 2048 + wave * 512];               // wave-uniform base
        __builtin_amdgcn_global_load_lds(
            (const __attribute__((address_space(1))) unsigned int*)gsrc,
            (__attribute__((address_space(3))) unsigned int*)ldst, 16, 0, 0);
    }
    __syncthreads();

    const int m = lane & 15, quad = lane >> 4;
    f32x4 acc[4];
#pragma unroll
    for (int ct = 0; ct < 4; ++ct) acc[ct] = (f32x4){0.f, 0.f, 0.f, 0.f};

#pragma unroll
    for (int k = 0; k < NK; ++k) {
#pragma unroll
        for (int cct = 0; cct < 2; ++cct) {
            bf16x8 A = *(const bf16x8*)&smem[(size_t)(k * 64 + wave * 16 + m) * 64
                                             + (((cct * 4 + quad) ^ (m & 7)) * 8)];
#pragma unroll
            for (int ct = 0; ct < 4; ++ct) {
                bf16x8 B = *(const bf16x8*)(wpack + (size_t)(((k * 2 + cct) * 4 + ct) * 64 + lane) * 8);
                acc[ct] = __builtin_amdgcn_mfma_f32_16x16x32_bf16(A, B, acc[ct], 0, 0, 0);
            }
        }
    }

#pragma unroll
    for (int ct = 0; ct < 4; ++ct) {
        const int c = ct * 16 + m;
        const float bv = bias[c];
#pragma unroll
        for (int r = 0; r < 4; ++r) {
            int n = n0 + wave * 16 + quad * 4 + r;
            if (n < N_NODES) {
                float* op = out + ((size_t)b * N_NODES + n) * CH + c;
                float v = acc[ct][r];
                if (ACCUM) v += __builtin_nontemporal_load(op);
                else       v += bv;
                __builtin_nontemporal_store(v, op);
            }
        }
    }
}

extern "C" void kernel_launch(void* const* d_in, const int* in_sizes, int n_in,
                              void* d_out, int out_size, void* d_ws, size_t ws_size,
                              hipStream_t stream) {
    const float* x    = (const float*)d_in[0];   // [B,N,C]
    const int*   ei   = (const int*)d_in[1];     // [2,E]: row0=dst, row1=src
    const float* ew   = (const float*)d_in[2];   // [E]
    const float* W    = (const float*)d_in[3];   // [K,64,64]
    const float* bias = (const float*)d_in[4];   // [64]
    float* out = (float*)d_out;

    const int* dst = ei;
    const int* src = ei + N_EDGES;

    const size_t SB = TELEMS * sizeof(u16);      // 51.2 MB per t-buffer
    const size_t EXTRA = 2 * 200192 + (size_t)N_EDGES * sizeof(int2) + 49664;
    const size_t NEED_PRIMARY = 6 * SB + EXTRA;  // ~314.3 MB
    const bool primary = (ws_size >= NEED_PRIMARY);
    const int nbuf = primary ? 6 : 3;

    char* ws = (char*)d_ws;
    size_t off = 0;
    u16* tbase = (u16*)(ws + off); off += (size_t)nbuf * SB;   // t0(=x bf16), t1..
    int* row_ptr = (int*)(ws + off); off += 200192;
    int* cursor  = (int*)(ws + off); off += 200192;
    int2* edges  = (int2*)(ws + off); off += (size_t)N_EDGES * sizeof(int2);
    u16* wpack   = (u16*)(ws + off); off += 49664;
    (void)off; (void)n_in; (void)in_sizes; (void)out_size;

    // ---- CSR build + precompute (fused launches) ----
    (void)hipMemsetAsync(cursor, 0, (size_t)N_NODES * sizeof(int), stream);
    hist_cast_kernel<<<HIST_BLOCKS + CAST_BLOCKS, 256, 0, stream>>>(dst, cursor, x, tbase);
    scan_kernel<<<1, 1024, 0, stream>>>(cursor, row_ptr, N_NODES);
    scatter_pack_kernel<<<HIST_BLOCKS + PACK_BLOCKS, 256, 0, stream>>>(dst, src, ew, cursor,
                                                                       edges, W, wpack);

    const int SPMM_GRID = N_NODES / 4;           // 12500 blocks, 1 node per wave
    u16* t0 = tbase;
    if (primary) {
        u16* t1 = tbase + 1 * TELEMS;
        u16* t2 = tbase + 2 * TELEMS;
        u16* t3 = tbase + 3 * TELEMS;
        u16* t4 = tbase + 4 * TELEMS;
        u16* t5 = tbase + 5 * TELEMS;
        // chain A: batches 0-3 for all 5 steps (25.6 MB working set stays hot),
        // then chain B: batches 4-7. Halves are fully independent.
        for (int h = 0; h < 2; ++h) {
            spmm_kernel<false><<<SPMM_GRID, 256, 0, stream>>>(t0, nullptr, t1, row_ptr, edges, h);
            spmm_kernel<true ><<<SPMM_GRID, 256, 0, stream>>>(t1, t0, t2, row_ptr, edges, h);
            spmm_kernel<true ><<<SPMM_GRID, 256, 0, stream>>>(t2, t1, t3, row_ptr, edges, h);
            spmm_kernel<true ><<<SPMM_GRID, 256, 0, stream>>>(t3, t2, t4, row_ptr, edges, h);
            spmm_kernel<true ><<<SPMM_GRID, 256, 0, stream>>>(t4, t3, t5, row_ptr, edges, h);
        }
        out_gemm<6, false><<<GG, 256, 0, stream>>>(tbase, TELEMS, wpack, bias, out);
    } else {
        // fallback: 3 rotating buffers + incremental GEMM accumulation
        u16* t1 = tbase + 1 * TELEMS;
        u16* t2 = tbase + 2 * TELEMS;
        spmm_kernel<false><<<SPMM_GRID, 256, 0, stream>>>(t0, nullptr, t1, row_ptr, edges, 0);
        spmm_kernel<false><<<SPMM_GRID, 256, 0, stream>>>(t0, nullptr, t1, row_ptr, edges, 1);
        out_gemm<2, false><<<GG, 256, 0, stream>>>(t0, TELEMS, wpack, bias, out);          // bias + T0@W0 + T1@W1
        spmm_kernel<true ><<<SPMM_GRID, 256, 0, stream>>>(t1, t0, t2, row_ptr, edges, 0);  // T2 -> t2
        spmm_kernel<true ><<<SPMM_GRID, 256, 0, stream>>>(t1, t0, t2, row_ptr, edges, 1);
        out_gemm<1, true ><<<GG, 256, 0, stream>>>(t2, TELEMS, wpack + 2 * WSZ, bias, out);
        spmm_kernel<true ><<<SPMM_GRID, 256, 0, stream>>>(t2, t1, t0, row_ptr, edges, 0);  // T3 -> t0
        spmm_kernel<true ><<<SPMM_GRID, 256, 0, stream>>>(t2, t1, t0, row_ptr, edges, 1);
        out_gemm<1, true ><<<GG, 256, 0, stream>>>(t0, TELEMS, wpack + 3 * WSZ, bias, out);
        spmm_kernel<true ><<<SPMM_GRID, 256, 0, stream>>>(t0, t2, t1, row_ptr, edges, 0);  // T4 -> t1
        spmm_kernel<true ><<<SPMM_GRID, 256, 0, stream>>>(t0, t2, t1, row_ptr, edges, 1);
        out_gemm<1, true ><<<GG, 256, 0, stream>>>(t1, TELEMS, wpack + 4 * WSZ, bias, out);
        spmm_kernel<true ><<<SPMM_GRID, 256, 0, stream>>>(t1, t0, t2, row_ptr, edges, 0);  // T5 -> t2
        spmm_kernel<true ><<<SPMM_GRID, 256, 0, stream>>>(t1, t0, t2, row_ptr, edges, 1);
        out_gemm<1, true ><<<GG, 256, 0, stream>>>(t2, TELEMS, wpack + 5 * WSZ, bias, out);
    }
}